// Round 1
// baseline (15049.048 us; speedup 1.0000x reference)
//
#include <hip/hip_runtime.h>
#include <cstdint>
#include <cstddef>

#define L 512
#define TSTEPS 8192
#define NBLK 8
#define CPB 64      // columns per forward block
#define CHUNK 128
#define NCHUNK 64   // 8192 / 128

// ---- workspace layout (bytes) ----
static constexpr size_t OFF_SCORES = 0;                                             // [TSTEPS][L] f32 = 16 MiB
static constexpr size_t OFF_BP     = (size_t)TSTEPS * L * sizeof(float);            // [TSTEPS][L] u16 = 8 MiB
static constexpr size_t OFF_EXIT   = OFF_BP + (size_t)TSTEPS * L * sizeof(uint16_t);// [NCHUNK][L] u16
static constexpr size_t OFF_ENTRY  = OFF_EXIT + (size_t)NCHUNK * L * sizeof(uint16_t); // [NCHUNK] i32

// coherent (agent-scope, cache-bypassing) loads/stores for cross-block exchange
__device__ __forceinline__ float ld_coh(const float* p) {
  uint32_t u = __hip_atomic_load((const uint32_t*)p, __ATOMIC_RELAXED, __HIP_MEMORY_SCOPE_AGENT);
  return __uint_as_float(u);
}
__device__ __forceinline__ void st_coh(float* p, float v) {
  __hip_atomic_store((uint32_t*)p, __float_as_uint(v), __ATOMIC_RELAXED, __HIP_MEMORY_SCOPE_AGENT);
}

// ---------------- forward: max-only scan, 8 blocks x 512 threads ----------------
// block g owns columns [g*64, g*64+64); T column-slice resident in LDS (128 KB).
// Exchange medium: allScores rows, NaN(0xFFFFFFFF)-initialized; data-poll sync.
__global__ __launch_bounds__(512) void fwd_kernel(const float* __restrict__ feats,
                                                  const float* __restrict__ trans,
                                                  float* __restrict__ allScores) {
  extern __shared__ char smem[];
  float* Tl    = (float*)smem;                          // [L][CPB]
  float* s_lds = (float*)(smem + (size_t)L * CPB * 4);  // [L]
  float* red   = s_lds + L;                             // [8][64]

  const int g    = blockIdx.x;
  const int tid  = threadIdx.x;
  const int wave = tid >> 6;
  const int lane = tid & 63;
  const int q    = tid & 15;   // column quad: columns col0 + 4q .. 4q+3
  const int p    = tid >> 4;   // row group [0,32): rows p*16 .. p*16+15
  const int col0 = g * CPB;

  // stage T[:, col0:col0+64] into LDS, coalesced float4
  for (int idx = tid; idx < L * (CPB / 4); idx += 512) {
    int row = idx >> 4;
    int cq  = idx & 15;
    *(float4*)(Tl + row * CPB + cq * 4) =
        *(const float4*)(trans + (size_t)row * L + col0 + cq * 4);
  }
  // publish t=0 slice: scores[0] = feats[0]
  if (tid < CPB) {
    st_coh(allScores + col0 + tid, feats[col0 + tid]);
  }
  __syncthreads();

  for (int t = 1; t < TSTEPS; ++t) {
    // each wave polls+loads one 64-wide slice of scores[t-1]
    {
      const float* src = allScores + (size_t)(t - 1) * L + wave * 64 + lane;
      float v = ld_coh(src);
      while (__any(__float_as_uint(v) == 0xFFFFFFFFu)) v = ld_coh(src);
      s_lds[wave * 64 + lane] = v;
    }
    __syncthreads();

    float emis = 0.f;
    if (wave == 0) emis = feats[(size_t)t * L + col0 + lane];  // issued early, used late

    float sreg[16];
    #pragma unroll
    for (int r4 = 0; r4 < 4; ++r4)
      *(float4*)(sreg + r4 * 4) = *(const float4*)(s_lds + p * 16 + r4 * 4);

    float m0 = -INFINITY, m1 = -INFINITY, m2 = -INFINITY, m3 = -INFINITY;
    #pragma unroll
    for (int k = 0; k < 16; ++k) {
      float4 tv = *(const float4*)(Tl + (p * 16 + k) * CPB + q * 4);
      float sv = sreg[k];
      m0 = fmaxf(m0, sv + tv.x);
      m1 = fmaxf(m1, sv + tv.y);
      m2 = fmaxf(m2, sv + tv.z);
      m3 = fmaxf(m3, sv + tv.w);
    }
    // reduce over the 4 row-groups within this wave (lane bits 4,5)
    #pragma unroll
    for (int off = 16; off <= 32; off <<= 1) {
      m0 = fmaxf(m0, __shfl_xor(m0, off));
      m1 = fmaxf(m1, __shfl_xor(m1, off));
      m2 = fmaxf(m2, __shfl_xor(m2, off));
      m3 = fmaxf(m3, __shfl_xor(m3, off));
    }
    if (lane < 16) {
      float4 mv = {m0, m1, m2, m3};
      *(float4*)(red + wave * 64 + lane * 4) = mv;
    }
    __syncthreads();
    if (wave == 0) {
      float acc = red[lane];
      #pragma unroll
      for (int w = 1; w < 8; ++w) acc = fmaxf(acc, red[w * 64 + lane]);
      st_coh(allScores + (size_t)t * L + col0 + lane, acc + emis);
    }
    // waves 1..7 run ahead into the next poll; sync at top-of-loop barrier order is
    // preserved by the __syncthreads() pair (s_lds regions are per-wave disjoint).
  }
}

// ---------------- backpointers: fully parallel recompute ----------------
// bp[t][j] = first argmax_i (scores[t-1][i] + T[i][j]); identical arithmetic to ref.
__global__ __launch_bounds__(512) void bp_kernel(const float* __restrict__ trans,
                                                 const float* __restrict__ allScores,
                                                 uint16_t* __restrict__ bp) {
  extern __shared__ char smem[];
  float* Tl    = (float*)smem;                          // [L][CPB]
  float* s_lds = (float*)(smem + (size_t)L * CPB * 4);  // [L]
  float* red_v = s_lds + L;                             // [8][64]
  int*   red_i = (int*)(red_v + 8 * 64);                // [8][64]

  const int cb   = blockIdx.x & 7;
  const int tt   = blockIdx.x >> 3;
  const int tid  = threadIdx.x;
  const int wave = tid >> 6, lane = tid & 63;
  const int q = tid & 15, p = tid >> 4;
  const int col0 = cb * CPB;

  for (int idx = tid; idx < L * (CPB / 4); idx += 512) {
    int row = idx >> 4, cq = idx & 15;
    *(float4*)(Tl + row * CPB + cq * 4) =
        *(const float4*)(trans + (size_t)row * L + col0 + cq * 4);
  }
  __syncthreads();

  const int t0 = tt * 32;
  for (int dt = 0; dt < 32; ++dt) {
    int t = t0 + dt;
    if (t == 0) continue;  // uniform across block
    if (tid < L) s_lds[tid] = allScores[(size_t)(t - 1) * L + tid];
    __syncthreads();

    float bv[4]; int bi[4];
    #pragma unroll
    for (int j = 0; j < 4; ++j) { bv[j] = -INFINITY; bi[j] = 0; }
    #pragma unroll
    for (int k = 0; k < 16; ++k) {
      int i = p * 16 + k;
      float sv = s_lds[i];
      float4 tv = *(const float4*)(Tl + i * CPB + q * 4);
      float c0 = sv + tv.x, c1 = sv + tv.y, c2 = sv + tv.z, c3 = sv + tv.w;
      if (c0 > bv[0]) { bv[0] = c0; bi[0] = i; }
      if (c1 > bv[1]) { bv[1] = c1; bi[1] = i; }
      if (c2 > bv[2]) { bv[2] = c2; bi[2] = i; }
      if (c3 > bv[3]) { bv[3] = c3; bi[3] = i; }
    }
    #pragma unroll
    for (int off = 16; off <= 32; off <<= 1) {
      #pragma unroll
      for (int j = 0; j < 4; ++j) {
        float ov = __shfl_xor(bv[j], off);
        int   oi = __shfl_xor(bi[j], off);
        bool take = (ov > bv[j]) || (ov == bv[j] && oi < bi[j]);
        bv[j] = take ? ov : bv[j];
        bi[j] = take ? oi : bi[j];
      }
    }
    if (lane < 16) {
      #pragma unroll
      for (int j = 0; j < 4; ++j) {
        red_v[wave * 64 + lane * 4 + j] = bv[j];
        red_i[wave * 64 + lane * 4 + j] = bi[j];
      }
    }
    __syncthreads();
    if (wave == 0) {
      float rv = red_v[lane]; int ri = red_i[lane];
      #pragma unroll
      for (int w = 1; w < 8; ++w) {
        float ov = red_v[w * 64 + lane]; int oi = red_i[w * 64 + lane];
        bool take = (ov > rv) || (ov == rv && oi < ri);
        rv = take ? ov : rv; ri = take ? oi : ri;
      }
      bp[(size_t)t * L + col0 + lane] = (uint16_t)ri;
    }
    __syncthreads();  // protect s_lds before next dt
  }
}

// ---------------- backtrack phase A: per-chunk label maps ----------------
__global__ __launch_bounds__(512) void exitmap_kernel(const uint16_t* __restrict__ bp,
                                                      uint16_t* __restrict__ cexit) {
  extern __shared__ char smem[];
  uint16_t* bpl = (uint16_t*)smem;  // [nrows][L]
  const int c = blockIdx.x, tid = threadIdx.x;
  const int lo = c * CHUNK;
  const int hi = min(lo + CHUNK, TSTEPS - 1);
  const int nrows = hi - lo;  // 128 (127 for last chunk)
  const uint32_t* src = (const uint32_t*)(bp + (size_t)(lo + 1) * L);
  uint32_t* dst = (uint32_t*)bpl;
  for (int idx = tid; idx < nrows * (L / 2); idx += 512) dst[idx] = src[idx];
  __syncthreads();
  int e = tid;  // entry tag at time hi
  for (int r = nrows - 1; r >= 0; --r) e = bpl[r * L + e];
  cexit[(size_t)c * L + tid] = (uint16_t)e;  // tag at time lo
}

// ---------------- backtrack phase B: final argmax + chunk composition ----------------
__global__ __launch_bounds__(64) void compose_kernel(const float* __restrict__ allScores,
                                                     const uint16_t* __restrict__ cexit,
                                                     int* __restrict__ entryTag,
                                                     float* __restrict__ out) {
  const int lane = threadIdx.x;
  float bv = -INFINITY; int bi = 0;
  #pragma unroll
  for (int r = 0; r < 8; ++r) {
    int i = r * 64 + lane;
    float v = allScores[(size_t)(TSTEPS - 1) * L + i];
    if (v > bv) { bv = v; bi = i; }   // ascending i per lane -> first max
  }
  #pragma unroll
  for (int off = 1; off < 64; off <<= 1) {
    float ov = __shfl_xor(bv, off);
    int   oi = __shfl_xor(bi, off);
    bool take = (ov > bv) || (ov == bv && oi < bi);
    bv = take ? ov : bv; bi = take ? oi : bi;
  }
  if (lane == 0) {
    out[0] = bv;                        // viterbi_score
    out[1 + (TSTEPS - 1)] = (float)bi;  // path[T-1]
    int e = bi;
    entryTag[NCHUNK - 1] = e;
    for (int c = NCHUNK - 1; c >= 1; --c) {
      e = cexit[(size_t)c * L + e];
      entryTag[c - 1] = e;
    }
  }
}

// ---------------- backtrack phase C: per-chunk path extraction ----------------
__global__ __launch_bounds__(512) void extract_kernel(const uint16_t* __restrict__ bp,
                                                      const int* __restrict__ entryTag,
                                                      float* __restrict__ out) {
  extern __shared__ char smem[];
  uint16_t* bpl = (uint16_t*)smem;
  const int c = blockIdx.x, tid = threadIdx.x;
  const int lo = c * CHUNK;
  const int hi = min(lo + CHUNK, TSTEPS - 1);
  const int nrows = hi - lo;
  const uint32_t* src = (const uint32_t*)(bp + (size_t)(lo + 1) * L);
  uint32_t* dst = (uint32_t*)bpl;
  for (int idx = tid; idx < nrows * (L / 2); idx += 512) dst[idx] = src[idx];
  __syncthreads();
  if (tid == 0) {
    int e = entryTag[c];  // tag at time hi
    for (int t = hi - 1; t >= lo; --t) {
      e = bpl[(t - lo) * L + e];  // bp[t+1][e]
      out[1 + t] = (float)e;
    }
  }
}

extern "C" void kernel_launch(void* const* d_in, const int* in_sizes, int n_in,
                              void* d_out, int out_size, void* d_ws, size_t ws_size,
                              hipStream_t stream) {
  const float* feats = (const float*)d_in[0];
  const float* trans = (const float*)d_in[1];
  float* out = (float*)d_out;
  char* ws = (char*)d_ws;
  float*    allScores = (float*)(ws + OFF_SCORES);
  uint16_t* bp        = (uint16_t*)(ws + OFF_BP);
  uint16_t* cexit     = (uint16_t*)(ws + OFF_EXIT);
  int*      entryTag  = (int*)(ws + OFF_ENTRY);

  const int FWD_LDS = L * CPB * 4 + L * 4 + 8 * 64 * 4;               // 135168
  const int BP_LDS  = L * CPB * 4 + L * 4 + 8 * 64 * 4 + 8 * 64 * 4;  // 137216
  const int CH_LDS  = CHUNK * L * 2;                                  // 131072

  hipFuncSetAttribute((const void*)fwd_kernel,     hipFuncAttributeMaxDynamicSharedMemorySize, FWD_LDS);
  hipFuncSetAttribute((const void*)bp_kernel,      hipFuncAttributeMaxDynamicSharedMemorySize, BP_LDS);
  hipFuncSetAttribute((const void*)exitmap_kernel, hipFuncAttributeMaxDynamicSharedMemorySize, CH_LDS);
  hipFuncSetAttribute((const void*)extract_kernel, hipFuncAttributeMaxDynamicSharedMemorySize, CH_LDS);

  // NaN-sentinel the score exchange buffer (replay-safe; part of the graph)
  hipMemsetAsync(allScores, 0xFF, (size_t)TSTEPS * L * sizeof(float), stream);

  fwd_kernel<<<NBLK, 512, FWD_LDS, stream>>>(feats, trans, allScores);
  bp_kernel<<<(TSTEPS / 32) * 8, 512, BP_LDS, stream>>>(trans, allScores, bp);
  exitmap_kernel<<<NCHUNK, 512, CH_LDS, stream>>>(bp, cexit);
  compose_kernel<<<1, 64, 0, stream>>>(allScores, cexit, entryTag, out);
  extract_kernel<<<NCHUNK, 512, CH_LDS, stream>>>(bp, entryTag, out);
}